// Round 6
// baseline (1845.553 us; speedup 1.0000x reference)
//
#include <hip/hip_runtime.h>

// ---------------------------------------------------------------------------
// GraphTransformer on MI355X, v6 = R4 kernel (best, 485us) + two BW probes
// that intentionally exceed the harness fill duration (~676us) so their
// rocprof counters surface in the top-5 table.
// ---------------------------------------------------------------------------

typedef __bf16 bf16x8 __attribute__((ext_vector_type(8)));
typedef float  f32x16 __attribute__((ext_vector_type(16)));
typedef float  f32x4  __attribute__((ext_vector_type(4)));

#define GN 16384
#define GD 128
#define BM 128
#define BK 32
#define KSPLIT 8
#define KRANGE (GN / KSPLIT)   // 2048
#define NIT (KRANGE / BK)      // 64
#define NSUP (NIT / 2)         // 32

__device__ __forceinline__ unsigned short f2bf(float f) {
    unsigned u = __float_as_uint(f);
    unsigned r = (u + 0x7FFFu + ((u >> 16) & 1u)) >> 16;
    return (unsigned short)r;
}
__device__ __forceinline__ float bf2f(unsigned short u) {
    return __uint_as_float(((unsigned)u) << 16);
}

typedef __attribute__((address_space(1))) const void glb_cv;
typedef __attribute__((address_space(3))) void lds_v;
__device__ __forceinline__ void gload_lds16(const void* g, void* l) {
    __builtin_amdgcn_global_load_lds((glb_cv*)g, (lds_v*)l, 16, 0, 0);
}

// ---------------------------------------------------------------------------
// PROBE 1: linear stream over adj, 5 passes. ~900us if healthy -> top-5 row.
// ---------------------------------------------------------------------------
__global__ __launch_bounds__(256) void probe_lin(const float* __restrict__ adj,
                                                 float* __restrict__ sink) {
    const long tid = (long)blockIdx.x * 256 + threadIdx.x;
    const long stride = (long)gridDim.x * 256;
    float s = 0.f;
    for (int rep = 0; rep < 5; ++rep) {
        for (long i = tid; i < (long)GN * GN / 4; i += stride) {
            const f32x4 v = __builtin_nontemporal_load((const f32x4*)(adj + i * 4));
            s += v[0] + v[1] + v[2] + v[3];
        }
    }
    sink[tid] = s;
}

// ---------------------------------------------------------------------------
// PROBE 2: exact gemm A-access pattern (32 rows/wave x 16B bursts, 64KB row
// stride, XCD-pinned k-slices), 2 passes. Visible in top-5 iff pattern-bound.
// ---------------------------------------------------------------------------
__global__ __launch_bounds__(256) void probe_str(const float* __restrict__ adj,
                                                 float* __restrict__ sink) {
    const int t = threadIdx.x, b = blockIdx.x;
    const int ks = b & 7, bmi = b >> 3;
    const long rowbase = (long)bmi * BM;
    const int kb0 = ks * KRANGE;
    const float* abase = adj + (rowbase + (t >> 1)) * 16384L + kb0 + (t & 1) * 16;
    float s = 0.f;
    for (int rep = 0; rep < 2; ++rep) {
        for (int it = 0; it < NIT; ++it) {
#pragma unroll
            for (int p = 0; p < 4; ++p) {
                const f32x4 v = __builtin_nontemporal_load(
                    (const f32x4*)(abase + it * BK + p * 4));
                s += v[0] + v[1] + v[2] + v[3];
            }
        }
    }
    sink[b * 256 + t] = s;
}

// ---------------------------------------------------------------------------
// P1: x [16384][128] fp32 -> xh/xl bf16, transposed to [col][k] per 32-k tile,
// pre-swizzled: idx = tile*4096 + c*32 + ((g^((c>>1)&3))<<3) + (k&7), g=(k>>3)&3
// ---------------------------------------------------------------------------
__global__ void prep_x(const float* __restrict__ x,
                       unsigned short* __restrict__ xh,
                       unsigned short* __restrict__ xl) {
    const int kt = blockIdx.x;   // 0..511
    const int c  = threadIdx.x;  // 0..127
    float v[32];
#pragma unroll
    for (int i = 0; i < 32; ++i)
        v[i] = x[((long)kt * 32 + i) * 128 + c];
    const int f = (c >> 1) & 3;
    unsigned short* oh = xh + (long)kt * 4096 + c * 32;
    unsigned short* ol = xl + (long)kt * 4096 + c * 32;
#pragma unroll
    for (int g = 0; g < 4; ++g) {
        uint4 ph, pl;
        unsigned hp[4], lp[4];
#pragma unroll
        for (int q = 0; q < 4; ++q) {
            float a = v[g * 8 + q * 2], b = v[g * 8 + q * 2 + 1];
            unsigned short ha = f2bf(a), hb = f2bf(b);
            float la = a - bf2f(ha), lb = b - bf2f(hb);
            hp[q] = (unsigned)ha | ((unsigned)hb << 16);
            lp[q] = (unsigned)f2bf(la) | ((unsigned)f2bf(lb) << 16);
        }
        ph.x = hp[0]; ph.y = hp[1]; ph.z = hp[2]; ph.w = hp[3];
        pl.x = lp[0]; pl.y = lp[1]; pl.z = lp[2]; pl.w = lp[3];
        const int gp = g ^ f;
        *(uint4*)&oh[gp * 8] = ph;
        *(uint4*)&ol[gp * 8] = pl;
    }
}

// ---------------------------------------------------------------------------
// G: cpart[ks][i][d] = adj[i, ks-range] @ x[ks-range, d]   (R4 version)
// ---------------------------------------------------------------------------
__global__ __launch_bounds__(256, 3) void gemm_adj(
    const float* __restrict__ adj,
    const unsigned short* __restrict__ xh,
    const unsigned short* __restrict__ xl,
    float* __restrict__ cpart) {
    __shared__ __align__(16) unsigned short Ah[BM * BK];
    __shared__ __align__(16) unsigned short Al[BM * BK];
    __shared__ __align__(16) unsigned short Bh[GD * BK];
    __shared__ __align__(16) unsigned short Bl[GD * BK];

    const int t   = threadIdx.x;
    const int b   = blockIdx.x;
    const int ks  = b & 7;
    const int bmi = b >> 3;
    const long rowbase = (long)bmi * BM;
    const int kb0 = ks * KRANGE;
    const int lane = t & 63, wid = t >> 6;
    const int ra = t >> 1;           // A row 0..127 (2 threads/row)
    const int sub = (t & 1) * 4;     // float sub-offset within 8-float group

    f32x16 acc[4];
#pragma unroll
    for (int n = 0; n < 4; ++n)
#pragma unroll
        for (int e = 0; e < 16; ++e) acc[n][e] = 0.0f;

    const float* abase = adj + (rowbase + ra) * 16384L + kb0;
    f32x4 pref[8];
#pragma unroll
    for (int cc = 0; cc < 8; ++cc)
        pref[cc] = __builtin_nontemporal_load(
            (const f32x4*)(abase + cc * 8 + sub));

    const int rsw = (ra >> 1) & 3;
    const int rm  = wid * 32 + (lane & 31);   // MFMA row
    const int rswm = (rm >> 1) & 3;

    for (int sup = 0; sup < NSUP; ++sup) {
#pragma unroll
        for (int half = 0; half < 2; ++half) {
            const int it = sup * 2 + half;
            const int kb = kb0 + it * BK;
            __syncthreads();
            // B stage: async global->LDS (pre-swizzled, linear)
            {
                const char* sh = (const char*)(xh + (long)(kb >> 5) * 4096);
                const char* sl = (const char*)(xl + (long)(kb >> 5) * 4096);
#pragma unroll
                for (int j = 0; j < 2; ++j) {
                    const int seg = wid + j * 4;
                    gload_lds16(sh + seg * 1024 + lane * 16, ((char*)Bh) + seg * 1024);
                    gload_lds16(sl + seg * 1024 + lane * 16, ((char*)Bl) + seg * 1024);
                }
            }
            // A stage: convert this half's 4 chunks -> bf16 hi/lo, swizzled
#pragma unroll
            for (int c2 = 0; c2 < 4; ++c2) {
                const f32x4 v = pref[half * 4 + c2];
                unsigned hu[2], lu[2];
#pragma unroll
                for (int q = 0; q < 2; ++q) {
                    unsigned short ha = f2bf(v[2 * q]), hb = f2bf(v[2 * q + 1]);
                    float la = v[2 * q] - bf2f(ha), lb = v[2 * q + 1] - bf2f(hb);
                    hu[q] = (unsigned)ha | ((unsigned)hb << 16);
                    lu[q] = (unsigned)f2bf(la) | ((unsigned)f2bf(lb) << 16);
                }
                const int gp = c2 ^ rsw;
                const int idx = ra * 32 + gp * 8 + sub;
                uint2 H2, L2;
                H2.x = hu[0]; H2.y = hu[1];
                L2.x = lu[0]; L2.y = lu[1];
                *(uint2*)&Ah[idx] = H2;
                *(uint2*)&Al[idx] = L2;
            }
            __syncthreads();
            if (half == 1 && sup + 1 < NSUP) {
#pragma unroll
                for (int cc = 0; cc < 8; ++cc)
                    pref[cc] = __builtin_nontemporal_load(
                        (const f32x4*)(abase + (sup + 1) * 64 + cc * 8 + sub));
            }
            // MFMA phase
#pragma unroll
            for (int s = 0; s < 2; ++s) {
                const int hh = 2 * s + (lane >> 5);
                bf16x8 am, al2;
                am  = *(const bf16x8*)&Ah[rm * 32 + (hh ^ rswm) * 8];
                al2 = *(const bf16x8*)&Al[rm * 32 + (hh ^ rswm) * 8];
#pragma unroll
                for (int n = 0; n < 4; ++n) {
                    const int c = n * 32 + (lane & 31);
                    const int gp = hh ^ ((c >> 1) & 3);
                    const bf16x8 bn  = *(const bf16x8*)&Bh[c * 32 + gp * 8];
                    const bf16x8 bl4 = *(const bf16x8*)&Bl[c * 32 + gp * 8];
                    acc[n] = __builtin_amdgcn_mfma_f32_32x32x16_bf16(am, bn, acc[n], 0, 0, 0);
                    acc[n] = __builtin_amdgcn_mfma_f32_32x32x16_bf16(am, bl4, acc[n], 0, 0, 0);
                    acc[n] = __builtin_amdgcn_mfma_f32_32x32x16_bf16(al2, bn, acc[n], 0, 0, 0);
                }
            }
        }
    }
    float* cp = cpart + (long)ks * GN * GD;
#pragma unroll
    for (int n = 0; n < 4; ++n) {
        const int c = n * 32 + (lane & 31);
#pragma unroll
        for (int e = 0; e < 16; ++e) {
            const int rl = wid * 32 + (e & 3) + 8 * (e >> 2) + 4 * (lane >> 5);
            __builtin_nontemporal_store(acc[n][e], &cp[(rowbase + rl) * (long)GD + c]);
        }
    }
}

// ---------------------------------------------------------------------------
// T: fused tail (unchanged from R4).
// ---------------------------------------------------------------------------
__global__ __launch_bounds__(256, 2) void tail_fused(
    const float* __restrict__ cpart,
    const float* __restrict__ Wq, const float* __restrict__ Wk,
    const float* __restrict__ Wv, const float* __restrict__ Wo,
    const float* __restrict__ ln1s,
    const float* __restrict__ W1, const float* __restrict__ W2,
    const float* __restrict__ ln2s, const float* __restrict__ Wout,
    float* __restrict__ out) {
    __shared__ __align__(16) float H[32][128];
    __shared__ __align__(16) float C[32][128];
    __shared__ __align__(16) float FB[32 * 256];
    float (*B1)[128] = (float (*)[128])FB;

    const int t = threadIdx.x;
    const int ogrp = t & 31, rowgrp = t >> 5;
    const int o4 = ogrp * 4, rbase = rowgrp * 4;
    const long r0 = (long)blockIdx.x * 32;

#pragma unroll
    for (int j = 0; j < 4; ++j) {
        const int p = t + 256 * j;
        const int row = p >> 5, c4 = (p & 31) * 4;
        f32x4 s = __builtin_nontemporal_load(
            (const f32x4*)&cpart[(r0 + row) * 128 + c4]);
#pragma unroll
        for (int ks = 1; ks < KSPLIT; ++ks) {
            f32x4 v = __builtin_nontemporal_load(
                (const f32x4*)&cpart[((long)ks * GN + r0 + row) * 128 + c4]);
            s += v;
        }
        *(f32x4*)&H[row][c4] = s;
    }
    __syncthreads();

    float qa[4][4] = {}, ka[4][4] = {};
    for (int dg = 0; dg < 32; ++dg) {
        f32x4 h4[4];
#pragma unroll
        for (int rr = 0; rr < 4; ++rr) h4[rr] = *(const f32x4*)&H[rbase + rr][dg * 4];
#pragma unroll
        for (int i = 0; i < 4; ++i) {
            const int d = dg * 4 + i;
            const f32x4 wq = *(const f32x4*)&Wq[d * 128 + o4];
            const f32x4 wk = *(const f32x4*)&Wk[d * 128 + o4];
#pragma unroll
            for (int rr = 0; rr < 4; ++rr) {
                const float hv = h4[rr][i];
                qa[rr][0] += hv * wq[0]; qa[rr][1] += hv * wq[1];
                qa[rr][2] += hv * wq[2]; qa[rr][3] += hv * wq[3];
                ka[rr][0] += hv * wk[0]; ka[rr][1] += hv * wk[1];
                ka[rr][2] += hv * wk[2]; ka[rr][3] += hv * wk[3];
            }
        }
    }
    float w[4][4];
#pragma unroll
    for (int rr = 0; rr < 4; ++rr) {
        float s0 = qa[rr][0] * ka[rr][0] * 0.25f;
        float s1 = qa[rr][1] * ka[rr][1] * 0.25f;
        float s2 = qa[rr][2] * ka[rr][2] * 0.25f;
        float s3 = qa[rr][3] * ka[rr][3] * 0.25f;
        float m = fmaxf(fmaxf(s0, s1), fmaxf(s2, s3));
        m = fmaxf(m, __shfl_xor(m, 1, 64));
        float e0 = __expf(s0 - m), e1 = __expf(s1 - m);
        float e2 = __expf(s2 - m), e3 = __expf(s3 - m);
        float sum = e0 + e1 + e2 + e3;
        sum += __shfl_xor(sum, 1, 64);
        float inv = 1.0f / sum;
        w[rr][0] = e0 * inv; w[rr][1] = e1 * inv;
        w[rr][2] = e2 * inv; w[rr][3] = e3 * inv;
    }
    {
        float va[4][4] = {};
        for (int dg = 0; dg < 32; ++dg) {
            f32x4 h4[4];
#pragma unroll
            for (int rr = 0; rr < 4; ++rr) h4[rr] = *(const f32x4*)&H[rbase + rr][dg * 4];
#pragma unroll
            for (int i = 0; i < 4; ++i) {
                const int d = dg * 4 + i;
                const f32x4 wv = *(const f32x4*)&Wv[d * 128 + o4];
#pragma unroll
                for (int rr = 0; rr < 4; ++rr) {
                    const float hv = h4[rr][i];
                    va[rr][0] += hv * wv[0]; va[rr][1] += hv * wv[1];
                    va[rr][2] += hv * wv[2]; va[rr][3] += hv * wv[3];
                }
            }
        }
#pragma unroll
        for (int rr = 0; rr < 4; ++rr) {
            f32x4 a;
            a[0] = w[rr][0] * va[rr][0]; a[1] = w[rr][1] * va[rr][1];
            a[2] = w[rr][2] * va[rr][2]; a[3] = w[rr][3] * va[rr][3];
            *(f32x4*)&B1[rbase + rr][o4] = a;
        }
    }
    __syncthreads();
    {
        float oa[4][4] = {};
        for (int dg = 0; dg < 32; ++dg) {
            f32x4 h4[4];
#pragma unroll
            for (int rr = 0; rr < 4; ++rr) h4[rr] = *(const f32x4*)&B1[rbase + rr][dg * 4];
#pragma unroll
            for (int i = 0; i < 4; ++i) {
                const int d = dg * 4 + i;
                const f32x4 wo = *(const f32x4*)&Wo[d * 128 + o4];
#pragma unroll
                for (int rr = 0; rr < 4; ++rr) {
                    const float hv = h4[rr][i];
                    oa[rr][0] += hv * wo[0]; oa[rr][1] += hv * wo[1];
                    oa[rr][2] += hv * wo[2]; oa[rr][3] += hv * wo[3];
                }
            }
        }
        const f32x4 g1 = *(const f32x4*)&ln1s[o4];
#pragma unroll
        for (int rr = 0; rr < 4; ++rr) {
            const f32x4 hres = *(const f32x4*)&H[rbase + rr][o4];
            float u0 = oa[rr][0] + hres[0], u1 = oa[rr][1] + hres[1];
            float u2 = oa[rr][2] + hres[2], u3 = oa[rr][3] + hres[3];
            float s1 = u0 + u1 + u2 + u3;
            float s2 = u0 * u0 + u1 * u1 + u2 * u2 + u3 * u3;
#pragma unroll
            for (int mk = 1; mk < 32; mk <<= 1) {
                s1 += __shfl_xor(s1, mk, 64);
                s2 += __shfl_xor(s2, mk, 64);
            }
            const float mean = s1 * (1.f / 128.f);
            const float var  = s2 * (1.f / 128.f) - mean * mean;
            const float rstd = rsqrtf(var + 1e-6f);
            f32x4 cvr;
            cvr[0] = (u0 - mean) * rstd * g1[0]; cvr[1] = (u1 - mean) * rstd * g1[1];
            cvr[2] = (u2 - mean) * rstd * g1[2]; cvr[3] = (u3 - mean) * rstd * g1[3];
            *(f32x4*)&C[rbase + rr][o4] = cvr;
        }
    }
    __syncthreads();
#pragma unroll
    for (int h = 0; h < 2; ++h) {
        float fa[4][4] = {};
        for (int dg = 0; dg < 32; ++dg) {
            f32x4 h4[4];
#pragma unroll
            for (int rr = 0; rr < 4; ++rr) h4[rr] = *(const f32x4*)&C[rbase + rr][dg * 4];
#pragma unroll
            for (int i = 0; i < 4; ++i) {
                const int d = dg * 4 + i;
                const f32x4 w1 = *(const f32x4*)&W1[d * 256 + h * 128 + o4];
#pragma unroll
                for (int rr = 0; rr < 4; ++rr) {
                    const float hv = h4[rr][i];
                    fa[rr][0] += hv * w1[0]; fa[rr][1] += hv * w1[1];
                    fa[rr][2] += hv * w1[2]; fa[rr][3] += hv * w1[3];
                }
            }
        }
#pragma unroll
        for (int rr = 0; rr < 4; ++rr) {
            f32x4 a;
            a[0] = fmaxf(fa[rr][0], 0.f); a[1] = fmaxf(fa[rr][1], 0.f);
            a[2] = fmaxf(fa[rr][2], 0.f); a[3] = fmaxf(fa[rr][3], 0.f);
            *(f32x4*)&FB[(rbase + rr) * 256 + h * 128 + o4] = a;
        }
        __syncthreads();
    }
    {
        float ga[4][4] = {};
        for (int dg = 0; dg < 64; ++dg) {
            f32x4 f4[4];
#pragma unroll
            for (int rr = 0; rr < 4; ++rr)
                f4[rr] = *(const f32x4*)&FB[(rbase + rr) * 256 + dg * 4];
#pragma unroll
            for (int i = 0; i < 4; ++i) {
                const int d = dg * 4 + i;
                const f32x4 w2 = *(const f32x4*)&W2[d * 128 + o4];
#pragma unroll
                for (int rr = 0; rr < 4; ++rr) {
                    const float hv = f4[rr][i];
                    ga[rr][0] += hv * w2[0]; ga[rr][1] += hv * w2[1];
                    ga[rr][2] += hv * w2[2]; ga[rr][3] += hv * w2[3];
                }
            }
        }
        const f32x4 g2 = *(const f32x4*)&ln2s[o4];
#pragma unroll
        for (int rr = 0; rr < 4; ++rr) {
            const f32x4 cres = *(const f32x4*)&C[rbase + rr][o4];
            float u0 = ga[rr][0] + cres[0], u1 = ga[rr][1] + cres[1];
            float u2 = ga[rr][2] + cres[2], u3 = ga[rr][3] + cres[3];
            float s1 = u0 + u1 + u2 + u3;
            float s2 = u0 * u0 + u1 * u1 + u2 * u2 + u3 * u3;
#pragma unroll
            for (int mk = 1; mk < 32; mk <<= 1) {
                s1 += __shfl_xor(s1, mk, 64);
                s2 += __shfl_xor(s2, mk, 64);
            }
            const float mean = s1 * (1.f / 128.f);
            const float var  = s2 * (1.f / 128.f) - mean * mean;
            const float rstd = rsqrtf(var + 1e-6f);
            f32x4 cvr;
            cvr[0] = (u0 - mean) * rstd * g2[0]; cvr[1] = (u1 - mean) * rstd * g2[1];
            cvr[2] = (u2 - mean) * rstd * g2[2]; cvr[3] = (u3 - mean) * rstd * g2[3];
            *(f32x4*)&C[rbase + rr][o4] = cvr;
        }
    }
    __syncthreads();
    {
        const int r7 = t >> 3, ob = t & 7;
        float acc[5] = {0.f, 0.f, 0.f, 0.f, 0.f};
        for (int dg = 0; dg < 32; ++dg) {
            const f32x4 c4 = *(const f32x4*)&C[r7][dg * 4];
#pragma unroll
            for (int i = 0; i < 4; ++i) {
                const int d = dg * 4 + i;
                const float hv = c4[i];
#pragma unroll
                for (int jj = 0; jj < 5; ++jj)
                    acc[jj] += hv * Wout[d * 40 + ob + 8 * jj];
            }
        }
#pragma unroll
        for (int jj = 0; jj < 5; ++jj)
            out[(r0 + r7) * 40 + ob + 8 * jj] = acc[jj];
    }
}

// ---------------------------------------------------------------------------
extern "C" void kernel_launch(void* const* d_in, const int* in_sizes, int n_in,
                              void* d_out, int out_size, void* d_ws, size_t ws_size,
                              hipStream_t stream) {
    const float* x    = (const float*)d_in[0];
    const float* adj  = (const float*)d_in[1];
    const float* Wq   = (const float*)d_in[2];
    const float* Wk   = (const float*)d_in[3];
    const float* Wv   = (const float*)d_in[4];
    const float* Wo   = (const float*)d_in[5];
    const float* ln1s = (const float*)d_in[6];
    const float* W1   = (const float*)d_in[7];
    const float* W2   = (const float*)d_in[8];
    const float* ln2s = (const float*)d_in[9];
    const float* Wout = (const float*)d_in[10];

    char* ws = (char*)d_ws;
    unsigned short* xh = (unsigned short*)(ws);                  // 4 MB
    unsigned short* xl = (unsigned short*)(ws + (4L << 20));     // 4 MB
    float* cpart       = (float*)(ws + (8L << 20));              // 64 MB
    float* sink_lin    = (float*)(ws + (80L << 20));             // 2 MB
    float* sink_str    = (float*)(ws + (84L << 20));             // 1 MB

    // probes first (equal L3 footing), then the real pipeline
    probe_lin<<<2048, 256, 0, stream>>>(adj, sink_lin);
    probe_str<<<1024, 256, 0, stream>>>(adj, sink_str);
    prep_x<<<512, 128, 0, stream>>>(x, xh, xl);
    gemm_adj<<<1024, 256, 0, stream>>>(adj, xh, xl, cpart);
    tail_fused<<<512, 256, 0, stream>>>(cpart, Wq, Wk, Wv, Wo, ln1s,
                                        W1, W2, ln2s, Wout, (float*)d_out);
}

// Round 7
// 387.371 us; speedup vs baseline: 4.7643x; 4.7643x over previous
//
#include <hip/hip_runtime.h>

// ---------------------------------------------------------------------------
// GraphTransformer on MI355X, v7.
//   G: A staged as fp32 via global_load_lds with 256B-contiguous-per-row
//      instructions (fixes the 3.7 TB/s strided-pattern wall measured in R6);
//      hi/lo bf16 conversion at LDS-read time. B path identical to R4.
// ---------------------------------------------------------------------------

typedef __bf16 bf16x8 __attribute__((ext_vector_type(8)));
typedef float  f32x16 __attribute__((ext_vector_type(16)));
typedef float  f32x4  __attribute__((ext_vector_type(4)));

#define GN 16384
#define GD 128
#define BM 128
#define BK 32
#define KSPLIT 8
#define KRANGE (GN / KSPLIT)   // 2048
#define NSUP (KRANGE / 64)     // 32 superchunks of 64 k-floats

__device__ __forceinline__ unsigned short f2bf(float f) {
    unsigned u = __float_as_uint(f);
    unsigned r = (u + 0x7FFFu + ((u >> 16) & 1u)) >> 16;
    return (unsigned short)r;
}
__device__ __forceinline__ float bf2f(unsigned short u) {
    return __uint_as_float(((unsigned)u) << 16);
}

typedef __attribute__((address_space(1))) const void glb_cv;
typedef __attribute__((address_space(3))) void lds_v;
__device__ __forceinline__ void gload_lds16(const void* g, void* l) {
    __builtin_amdgcn_global_load_lds((glb_cv*)g, (lds_v*)l, 16, 0, 0);
}

// ---------------------------------------------------------------------------
// P1: x [16384][128] fp32 -> xh/xl bf16, transposed to [col][k] per 32-k tile,
// pre-swizzled: idx = tile*4096 + c*32 + ((g^((c>>1)&3))<<3) + (k&7), g=(k>>3)&3
// (unchanged from R4)
// ---------------------------------------------------------------------------
__global__ void prep_x(const float* __restrict__ x,
                       unsigned short* __restrict__ xh,
                       unsigned short* __restrict__ xl) {
    const int kt = blockIdx.x;   // 0..511
    const int c  = threadIdx.x;  // 0..127
    float v[32];
#pragma unroll
    for (int i = 0; i < 32; ++i)
        v[i] = x[((long)kt * 32 + i) * 128 + c];
    const int f = (c >> 1) & 3;
    unsigned short* oh = xh + (long)kt * 4096 + c * 32;
    unsigned short* ol = xl + (long)kt * 4096 + c * 32;
#pragma unroll
    for (int g = 0; g < 4; ++g) {
        uint4 ph, pl;
        unsigned hp[4], lp[4];
#pragma unroll
        for (int q = 0; q < 4; ++q) {
            float a = v[g * 8 + q * 2], b = v[g * 8 + q * 2 + 1];
            unsigned short ha = f2bf(a), hb = f2bf(b);
            float la = a - bf2f(ha), lb = b - bf2f(hb);
            hp[q] = (unsigned)ha | ((unsigned)hb << 16);
            lp[q] = (unsigned)f2bf(la) | ((unsigned)f2bf(lb) << 16);
        }
        ph.x = hp[0]; ph.y = hp[1]; ph.z = hp[2]; ph.w = hp[3];
        pl.x = lp[0]; pl.y = lp[1]; pl.z = lp[2]; pl.w = lp[3];
        const int gp = g ^ f;
        *(uint4*)&oh[gp * 8] = ph;
        *(uint4*)&ol[gp * 8] = pl;
    }
}

// ---------------------------------------------------------------------------
// G: cpart[ks][i][d] = adj[i, ks-range] @ x[ks-range, d]
// 1024 blocks (ks=b&7 XCD-pinned, bmi=b>>3), 256 thr (4 waves).
// Per superchunk (64 k): stage A fp32 [128][64] via 8 gload_lds/wave
// (each instr: 4 rows x 256B contiguous, source chunk-XOR'd by row&7) +
// stage B 2 half-tiles (R4 layout); barrier; 2x2 (half,s) MFMA slices with
// in-register fp32->bf16 hi/lo conversion; barrier.
// ---------------------------------------------------------------------------
__global__ __launch_bounds__(256, 2) void gemm_adj(
    const float* __restrict__ adj,
    const unsigned short* __restrict__ xh,
    const unsigned short* __restrict__ xl,
    float* __restrict__ cpart) {
    __shared__ __align__(16) float Afp[BM * 64];              // 32 KB
    __shared__ __align__(16) unsigned short Bh[2][GD * BK];   // 16 KB
    __shared__ __align__(16) unsigned short Bl[2][GD * BK];   // 16 KB

    const int t   = threadIdx.x;
    const int b   = blockIdx.x;
    const int ks  = b & 7;
    const int bmi = b >> 3;
    const long rowbase = (long)bmi * BM;
    const int kb0 = ks * KRANGE;
    const int lane = t & 63, wid = t >> 6;
    const int rm  = wid * 32 + (lane & 31);   // this lane's A row
    const int hl  = lane >> 5;
    const int l16 = lane & 15;                // chunk slot within instr
    const int rloc = lane >> 4;               // row-in-instr 0..3

    f32x16 acc[4];
#pragma unroll
    for (int n = 0; n < 4; ++n)
#pragma unroll
        for (int e = 0; e < 16; ++e) acc[n][e] = 0.0f;

    for (int sup = 0; sup < NSUP; ++sup) {
        const int kb = kb0 + sup * 64;
        // ---- stage A: 8 instrs/wave, 4 rows x 256B contiguous each ----
#pragma unroll
        for (int j = 0; j < 8; ++j) {
            const int rr  = wid * 32 + j * 4 + rloc;      // block-local row
            const int gch = l16 ^ (rr & 7);               // source 16B chunk
            const float* src = adj + (rowbase + rr) * 16384L + kb + gch * 4;
            gload_lds16(src, ((char*)Afp) + wid * 8192 + j * 1024);
        }
        // ---- stage B: two 32-k half-tiles, R4 pre-swizzled linear copy ----
#pragma unroll
        for (int half = 0; half < 2; ++half) {
            const long tile = (long)(kb0 >> 5) + sup * 2 + half;
            const char* sh = (const char*)(xh + tile * 4096);
            const char* sl = (const char*)(xl + tile * 4096);
#pragma unroll
            for (int j = 0; j < 2; ++j) {
                const int seg = wid + j * 4;
                gload_lds16(sh + seg * 1024 + lane * 16,
                            ((char*)&Bh[half][0]) + seg * 1024);
                gload_lds16(sl + seg * 1024 + lane * 16,
                            ((char*)&Bl[half][0]) + seg * 1024);
            }
        }
        __syncthreads();   // drains all gloads into LDS
        // ---- compute: 2 halves x 2 s-slices ----
#pragma unroll
        for (int half = 0; half < 2; ++half) {
#pragma unroll
            for (int s = 0; s < 2; ++s) {
                const int c16 = half * 8 + s * 4 + hl * 2;
                const int ca = (c16     ) ^ (rm & 7);
                const int cb = (c16 + 1) ^ (rm & 7);
                const f32x4 a0 = *(const f32x4*)((const char*)Afp + rm * 256 + ca * 16);
                const f32x4 a1 = *(const f32x4*)((const char*)Afp + rm * 256 + cb * 16);
                bf16x8 am, al;
#pragma unroll
                for (int jj = 0; jj < 4; ++jj) {
                    const __bf16 h0 = (__bf16)a0[jj];
                    am[jj] = h0;
                    al[jj] = (__bf16)(a0[jj] - (float)h0);
                    const __bf16 h1 = (__bf16)a1[jj];
                    am[4 + jj] = h1;
                    al[4 + jj] = (__bf16)(a1[jj] - (float)h1);
                }
                const int hh = s * 2 + hl;
#pragma unroll
                for (int n = 0; n < 4; ++n) {
                    const int c = n * 32 + (lane & 31);
                    const int bidx = c * 32 + (hh ^ ((c >> 1) & 3)) * 8;
                    const bf16x8 bn  = *(const bf16x8*)&Bh[half][bidx];
                    const bf16x8 bl4 = *(const bf16x8*)&Bl[half][bidx];
                    acc[n] = __builtin_amdgcn_mfma_f32_32x32x16_bf16(am, bn,  acc[n], 0, 0, 0);
                    acc[n] = __builtin_amdgcn_mfma_f32_32x32x16_bf16(am, bl4, acc[n], 0, 0, 0);
                    acc[n] = __builtin_amdgcn_mfma_f32_32x32x16_bf16(al, bn,  acc[n], 0, 0, 0);
                }
            }
        }
        __syncthreads();   // all waves done reading before next stage
    }
    // epilogue: C/D layout row=(e&3)+8*(e>>2)+4*(lane>>5), col=lane&31
    float* cp = cpart + (long)ks * GN * GD;
#pragma unroll
    for (int n = 0; n < 4; ++n) {
        const int c = n * 32 + (lane & 31);
#pragma unroll
        for (int e = 0; e < 16; ++e) {
            const int rl = wid * 32 + (e & 3) + 8 * (e >> 2) + 4 * (lane >> 5);
            __builtin_nontemporal_store(acc[n][e], &cp[(rowbase + rl) * (long)GD + c]);
        }
    }
}

// ---------------------------------------------------------------------------
// T: fused tail (unchanged from R4).
// ---------------------------------------------------------------------------
__global__ __launch_bounds__(256, 2) void tail_fused(
    const float* __restrict__ cpart,
    const float* __restrict__ Wq, const float* __restrict__ Wk,
    const float* __restrict__ Wv, const float* __restrict__ Wo,
    const float* __restrict__ ln1s,
    const float* __restrict__ W1, const float* __restrict__ W2,
    const float* __restrict__ ln2s, const float* __restrict__ Wout,
    float* __restrict__ out) {
    __shared__ __align__(16) float H[32][128];
    __shared__ __align__(16) float C[32][128];
    __shared__ __align__(16) float FB[32 * 256];
    float (*B1)[128] = (float (*)[128])FB;

    const int t = threadIdx.x;
    const int ogrp = t & 31, rowgrp = t >> 5;
    const int o4 = ogrp * 4, rbase = rowgrp * 4;
    const long r0 = (long)blockIdx.x * 32;

#pragma unroll
    for (int j = 0; j < 4; ++j) {
        const int p = t + 256 * j;
        const int row = p >> 5, c4 = (p & 31) * 4;
        f32x4 s = __builtin_nontemporal_load(
            (const f32x4*)&cpart[(r0 + row) * 128 + c4]);
#pragma unroll
        for (int ks = 1; ks < KSPLIT; ++ks) {
            f32x4 v = __builtin_nontemporal_load(
                (const f32x4*)&cpart[((long)ks * GN + r0 + row) * 128 + c4]);
            s += v;
        }
        *(f32x4*)&H[row][c4] = s;
    }
    __syncthreads();

    float qa[4][4] = {}, ka[4][4] = {};
    for (int dg = 0; dg < 32; ++dg) {
        f32x4 h4[4];
#pragma unroll
        for (int rr = 0; rr < 4; ++rr) h4[rr] = *(const f32x4*)&H[rbase + rr][dg * 4];
#pragma unroll
        for (int i = 0; i < 4; ++i) {
            const int d = dg * 4 + i;
            const f32x4 wq = *(const f32x4*)&Wq[d * 128 + o4];
            const f32x4 wk = *(const f32x4*)&Wk[d * 128 + o4];
#pragma unroll
            for (int rr = 0; rr < 4; ++rr) {
                const float hv = h4[rr][i];
                qa[rr][0] += hv * wq[0]; qa[rr][1] += hv * wq[1];
                qa[rr][2] += hv * wq[2]; qa[rr][3] += hv * wq[3];
                ka[rr][0] += hv * wk[0]; ka[rr][1] += hv * wk[1];
                ka[rr][2] += hv * wk[2]; ka[rr][3] += hv * wk[3];
            }
        }
    }
    float w[4][4];
#pragma unroll
    for (int rr = 0; rr < 4; ++rr) {
        float s0 = qa[rr][0] * ka[rr][0] * 0.25f;
        float s1 = qa[rr][1] * ka[rr][1] * 0.25f;
        float s2 = qa[rr][2] * ka[rr][2] * 0.25f;
        float s3 = qa[rr][3] * ka[rr][3] * 0.25f;
        float m = fmaxf(fmaxf(s0, s1), fmaxf(s2, s3));
        m = fmaxf(m, __shfl_xor(m, 1, 64));
        float e0 = __expf(s0 - m), e1 = __expf(s1 - m);
        float e2 = __expf(s2 - m), e3 = __expf(s3 - m);
        float sum = e0 + e1 + e2 + e3;
        sum += __shfl_xor(sum, 1, 64);
        float inv = 1.0f / sum;
        w[rr][0] = e0 * inv; w[rr][1] = e1 * inv;
        w[rr][2] = e2 * inv; w[rr][3] = e3 * inv;
    }
    {
        float va[4][4] = {};
        for (int dg = 0; dg < 32; ++dg) {
            f32x4 h4[4];
#pragma unroll
            for (int rr = 0; rr < 4; ++rr) h4[rr] = *(const f32x4*)&H[rbase + rr][dg * 4];
#pragma unroll
            for (int i = 0; i < 4; ++i) {
                const int d = dg * 4 + i;
                const f32x4 wv = *(const f32x4*)&Wv[d * 128 + o4];
#pragma unroll
                for (int rr = 0; rr < 4; ++rr) {
                    const float hv = h4[rr][i];
                    va[rr][0] += hv * wv[0]; va[rr][1] += hv * wv[1];
                    va[rr][2] += hv * wv[2]; va[rr][3] += hv * wv[3];
                }
            }
        }
#pragma unroll
        for (int rr = 0; rr < 4; ++rr) {
            f32x4 a;
            a[0] = w[rr][0] * va[rr][0]; a[1] = w[rr][1] * va[rr][1];
            a[2] = w[rr][2] * va[rr][2]; a[3] = w[rr][3] * va[rr][3];
            *(f32x4*)&B1[rbase + rr][o4] = a;
        }
    }
    __syncthreads();
    {
        float oa[4][4] = {};
        for (int dg = 0; dg < 32; ++dg) {
            f32x4 h4[4];
#pragma unroll
            for (int rr = 0; rr < 4; ++rr) h4[rr] = *(const f32x4*)&B1[rbase + rr][dg * 4];
#pragma unroll
            for (int i = 0; i < 4; ++i) {
                const int d = dg * 4 + i;
                const f32x4 wo = *(const f32x4*)&Wo[d * 128 + o4];
#pragma unroll
                for (int rr = 0; rr < 4; ++rr) {
                    const float hv = h4[rr][i];
                    oa[rr][0] += hv * wo[0]; oa[rr][1] += hv * wo[1];
                    oa[rr][2] += hv * wo[2]; oa[rr][3] += hv * wo[3];
                }
            }
        }
        const f32x4 g1 = *(const f32x4*)&ln1s[o4];
#pragma unroll
        for (int rr = 0; rr < 4; ++rr) {
            const f32x4 hres = *(const f32x4*)&H[rbase + rr][o4];
            float u0 = oa[rr][0] + hres[0], u1 = oa[rr][1] + hres[1];
            float u2 = oa[rr][2] + hres[2], u3 = oa[rr][3] + hres[3];
            float s1 = u0 + u1 + u2 + u3;
            float s2 = u0 * u0 + u1 * u1 + u2 * u2 + u3 * u3;
#pragma unroll
            for (int mk = 1; mk < 32; mk <<= 1) {
                s1 += __shfl_xor(s1, mk, 64);
                s2 += __shfl_xor(s2, mk, 64);
            }
            const float mean = s1 * (1.f / 128.f);
            const float var  = s2 * (1.f / 128.f) - mean * mean;
            const float rstd = rsqrtf(var + 1e-6f);
            f32x4 cvr;
            cvr[0] = (u0 - mean) * rstd * g1[0]; cvr[1] = (u1 - mean) * rstd * g1[1];
            cvr[2] = (u2 - mean) * rstd * g1[2]; cvr[3] = (u3 - mean) * rstd * g1[3];
            *(f32x4*)&C[rbase + rr][o4] = cvr;
        }
    }
    __syncthreads();
#pragma unroll
    for (int h = 0; h < 2; ++h) {
        float fa[4][4] = {};
        for (int dg = 0; dg < 32; ++dg) {
            f32x4 h4[4];
#pragma unroll
            for (int rr = 0; rr < 4; ++rr) h4[rr] = *(const f32x4*)&C[rbase + rr][dg * 4];
#pragma unroll
            for (int i = 0; i < 4; ++i) {
                const int d = dg * 4 + i;
                const f32x4 w1 = *(const f32x4*)&W1[d * 256 + h * 128 + o4];
#pragma unroll
                for (int rr = 0; rr < 4; ++rr) {
                    const float hv = h4[rr][i];
                    fa[rr][0] += hv * w1[0]; fa[rr][1] += hv * w1[1];
                    fa[rr][2] += hv * w1[2]; fa[rr][3] += hv * w1[3];
                }
            }
        }
#pragma unroll
        for (int rr = 0; rr < 4; ++rr) {
            f32x4 a;
            a[0] = fmaxf(fa[rr][0], 0.f); a[1] = fmaxf(fa[rr][1], 0.f);
            a[2] = fmaxf(fa[rr][2], 0.f); a[3] = fmaxf(fa[rr][3], 0.f);
            *(f32x4*)&FB[(rbase + rr) * 256 + h * 128 + o4] = a;
        }
        __syncthreads();
    }
    {
        float ga[4][4] = {};
        for (int dg = 0; dg < 64; ++dg) {
            f32x4 f4[4];
#pragma unroll
            for (int rr = 0; rr < 4; ++rr)
                f4[rr] = *(const f32x4*)&FB[(rbase + rr) * 256 + dg * 4];
#pragma unroll
            for (int i = 0; i < 4; ++i) {
                const int d = dg * 4 + i;
                const f32x4 w2 = *(const f32x4*)&W2[d * 128 + o4];
#pragma unroll
                for (int rr = 0; rr < 4; ++rr) {
                    const float hv = f4[rr][i];
                    ga[rr][0] += hv * w2[0]; ga[rr][1] += hv * w2[1];
                    ga[rr][2] += hv * w2[2]; ga[rr][3] += hv * w2[3];
                }
            }
        }
        const f32x4 g2 = *(const f32x4*)&ln2s[o4];
#pragma unroll
        for (int rr = 0; rr < 4; ++rr) {
            const f32x4 cres = *(const f32x4*)&C[rbase + rr][o4];
            float u0 = ga[rr][0] + cres[0], u1 = ga[rr][1] + cres[1];
            float u2 = ga[rr][2] + cres[2], u3 = ga[rr][3] + cres[3];
            float s1 = u0 + u1 + u2 + u3;
            float s2 = u0 * u0 + u1 * u1 + u2 * u2 + u3 * u3;
#pragma unroll
            for (int mk = 1; mk < 32; mk <<= 1) {
                s1 += __shfl_xor(s1, mk, 64);
                s2 += __shfl_xor(s2, mk, 64);
            }
            const float mean = s1 * (1.f / 128.f);
            const float var  = s2 * (1.f / 128.f) - mean * mean;
            const float rstd = rsqrtf(var + 1e-6f);
            f32x4 cvr;
            cvr[0] = (u0 - mean) * rstd * g2[0]; cvr[1] = (u1 - mean) * rstd * g2[1];
            cvr[2] = (u2 - mean) * rstd * g2[2]; cvr[3] = (u3 - mean) * rstd * g2[3];
            *(f32x4*)&C[rbase + rr][o4] = cvr;
        }
    }
    __syncthreads();
    {
        const int r7 = t >> 3, ob = t & 7;
        float acc[5] = {0.f, 0.f, 0.f, 0.f, 0.f};
        for (int dg = 0; dg < 32; ++dg) {
            const f32x4 c4 = *(const f32x4*)&C[r7][dg * 4];
#pragma unroll
            for (int i = 0; i < 4; ++i) {
                const int d = dg * 4 + i;
                const float hv = c4[i];
#pragma unroll
                for (int jj = 0; jj < 5; ++jj)
                    acc[jj] += hv * Wout[d * 40 + ob + 8 * jj];
            }
        }
#pragma unroll
        for (int jj = 0; jj < 5; ++jj)
            out[(r0 + r7) * 40 + ob + 8 * jj] = acc[jj];
    }
}

// ---------------------------------------------------------------------------
extern "C" void kernel_launch(void* const* d_in, const int* in_sizes, int n_in,
                              void* d_out, int out_size, void* d_ws, size_t ws_size,
                              hipStream_t stream) {
    const float* x    = (const float*)d_in[0];
    const float* adj  = (const float*)d_in[1];
    const float* Wq   = (const float*)d_in[2];
    const float* Wk   = (const float*)d_in[3];
    const float* Wv   = (const float*)d_in[4];
    const float* Wo   = (const float*)d_in[5];
    const float* ln1s = (const float*)d_in[6];
    const float* W1   = (const float*)d_in[7];
    const float* W2   = (const float*)d_in[8];
    const float* ln2s = (const float*)d_in[9];
    const float* Wout = (const float*)d_in[10];

    char* ws = (char*)d_ws;
    unsigned short* xh = (unsigned short*)(ws);                  // 4 MB
    unsigned short* xl = (unsigned short*)(ws + (4L << 20));     // 4 MB
    float* cpart       = (float*)(ws + (8L << 20));              // 64 MB

    prep_x<<<512, 128, 0, stream>>>(x, xh, xl);
    gemm_adj<<<1024, 256, 0, stream>>>(adj, xh, xl, cpart);
    tail_fused<<<512, 256, 0, stream>>>(cpart, Wq, Wk, Wv, Wo, ln1s,
                                        W1, W2, ln2s, Wout, (float*)d_out);
}